// Round 1
// baseline (1016.695 us; speedup 1.0000x reference)
//
#include <hip/hip_runtime.h>
#include <math.h>

// ---------------------------------------------------------------------------
// GCN: x1 = gelu(Agg(x@W1) + b1); out = Agg(x1@W2) + b2
// Agg(h)[i] = dinv[i] * sum_{e: dst=i} (ew_e * dinv[src_e]) * h[src_e]
//           + dinv[i]^2 * h[i]
// dinv[i] = rsqrt(1 + sum_{e: dst=i} ew_e)
// ---------------------------------------------------------------------------

#define CH1 256
#define CH2 128

__global__ void init_kernel(float* deg, int* counts, int n) {
    int i = blockIdx.x * blockDim.x + threadIdx.x;
    if (i < n) { deg[i] = 1.0f; counts[i] = 0; }
}

__global__ void count_kernel(const int* __restrict__ ei, const float* __restrict__ ew,
                             float* deg, int* counts, int E) {
    int e = blockIdx.x * blockDim.x + threadIdx.x;
    if (e < E) {
        int d = ei[E + e];           // dst row of edge_index
        atomicAdd(&counts[d], 1);
        atomicAdd(&deg[d], ew[e]);
    }
}

__global__ void dinv_kernel(float* deg, int n) {
    int i = blockIdx.x * blockDim.x + threadIdx.x;
    if (i < n) deg[i] = rsqrtf(deg[i]);   // deg >= 1 (self-loop), never 0
}

// ---- 3-phase exclusive scan of counts -> rowptr (chunk = 256) -------------
__global__ void scan_partial(const int* __restrict__ counts, int* partials, int n) {
    __shared__ int s[256];
    int i = blockIdx.x * 256 + threadIdx.x;
    s[threadIdx.x] = (i < n) ? counts[i] : 0;
    __syncthreads();
    for (int off = 128; off > 0; off >>= 1) {
        if (threadIdx.x < off) s[threadIdx.x] += s[threadIdx.x + off];
        __syncthreads();
    }
    if (threadIdx.x == 0) partials[blockIdx.x] = s[0];
}

__global__ void scan_serial(int* partials, int nb, int* rowptr, int n) {
    if (blockIdx.x == 0 && threadIdx.x == 0) {
        int run = 0;
        for (int i = 0; i < nb; ++i) { int t = partials[i]; partials[i] = run; run += t; }
        rowptr[n] = run;   // == E
    }
}

__global__ void scan_final(const int* __restrict__ counts, const int* __restrict__ partials,
                           int* rowptr, int* cursor, int n) {
    __shared__ int s[256];
    int i = blockIdx.x * 256 + threadIdx.x;
    int v = (i < n) ? counts[i] : 0;
    s[threadIdx.x] = v;
    __syncthreads();
    // Hillis-Steele inclusive scan
    for (int off = 1; off < 256; off <<= 1) {
        int t = (threadIdx.x >= off) ? s[threadIdx.x - off] : 0;
        __syncthreads();
        s[threadIdx.x] += t;
        __syncthreads();
    }
    if (i < n) {
        int excl = partials[blockIdx.x] + s[threadIdx.x] - v;
        rowptr[i] = excl;
        cursor[i] = excl;
    }
}

__global__ void scatter_kernel(const int* __restrict__ ei, const float* __restrict__ ew,
                               const float* __restrict__ dinv, int* cursor,
                               int* __restrict__ src_sorted, float* __restrict__ coef, int E) {
    int e = blockIdx.x * blockDim.x + threadIdx.x;
    if (e < E) {
        int s = ei[e];
        int d = ei[E + e];
        int pos = atomicAdd(&cursor[d], 1);
        src_sorted[pos] = s;
        coef[pos] = ew[e] * dinv[s];
    }
}

// ---- fp32 LDS-tiled GEMM: C[M,N] = A[M,K] @ B[K,N], K,N multiples of 64 ----
__global__ __launch_bounds__(256) void gemm_tile(const float* __restrict__ A,
                                                 const float* __restrict__ B,
                                                 float* __restrict__ C,
                                                 int M, int N, int K) {
    __shared__ float As[64][65];
    __shared__ float Bs[64][65];
    int tx = threadIdx.x & 15;
    int ty = threadIdx.x >> 4;
    int row0 = blockIdx.x * 64;
    int col0 = blockIdx.y * 64;
    float acc[4][4] = {};

    for (int k0 = 0; k0 < K; k0 += 64) {
#pragma unroll
        for (int i = 0; i < 4; ++i) {
            int r = ty + 16 * i;
            float4 va = {0.f, 0.f, 0.f, 0.f};
            if (row0 + r < M)
                va = *reinterpret_cast<const float4*>(A + (size_t)(row0 + r) * K + k0 + tx * 4);
            As[r][tx * 4 + 0] = va.x; As[r][tx * 4 + 1] = va.y;
            As[r][tx * 4 + 2] = va.z; As[r][tx * 4 + 3] = va.w;
            float4 vb = *reinterpret_cast<const float4*>(B + (size_t)(k0 + r) * N + col0 + tx * 4);
            Bs[r][tx * 4 + 0] = vb.x; Bs[r][tx * 4 + 1] = vb.y;
            Bs[r][tx * 4 + 2] = vb.z; Bs[r][tx * 4 + 3] = vb.w;
        }
        __syncthreads();
#pragma unroll 8
        for (int k = 0; k < 64; ++k) {
            float a[4], b[4];
#pragma unroll
            for (int i = 0; i < 4; ++i) a[i] = As[ty + 16 * i][k];
#pragma unroll
            for (int j = 0; j < 4; ++j) b[j] = Bs[k][tx + 16 * j];
#pragma unroll
            for (int i = 0; i < 4; ++i)
#pragma unroll
                for (int j = 0; j < 4; ++j) acc[i][j] += a[i] * b[j];
        }
        __syncthreads();
    }
#pragma unroll
    for (int i = 0; i < 4; ++i) {
        int r = row0 + ty + 16 * i;
        if (r < M) {
#pragma unroll
            for (int j = 0; j < 4; ++j)
                C[(size_t)r * N + col0 + tx + 16 * j] = acc[i][j];
        }
    }
}

__device__ __forceinline__ float gelu_exact(float x) {
    return 0.5f * x * (1.0f + erff(x * 0.70710678118654752f));
}

// ---- aggregation: one wave per node, CPL floats per lane -------------------
template <int C, int APPLY_GELU>
__global__ __launch_bounds__(256) void aggregate_kernel(
    const float* __restrict__ h, const int* __restrict__ rowptr,
    const int* __restrict__ srcs, const float* __restrict__ coef,
    const float* __restrict__ dinv, const float* __restrict__ bias,
    float* __restrict__ out, int n) {
    constexpr int CPL = C / 64;   // floats per lane (4 for C=256, 2 for C=128)
    int wid = threadIdx.x >> 6;
    int lane = threadIdx.x & 63;
    int node = blockIdx.x * 4 + wid;
    if (node >= n) return;

    int beg = rowptr[node];
    int end = rowptr[node + 1];
    float acc[CPL];
#pragma unroll
    for (int c = 0; c < CPL; ++c) acc[c] = 0.f;

    int e = beg;
    // 2-deep manual unroll so two gathers are in flight
    for (; e + 1 < end; e += 2) {
        int s0 = srcs[e];     float c0 = coef[e];
        int s1 = srcs[e + 1]; float c1 = coef[e + 1];
        const float* p0 = h + (size_t)s0 * C + lane * CPL;
        const float* p1 = h + (size_t)s1 * C + lane * CPL;
        float v0[CPL], v1[CPL];
        if (CPL == 4) {
            float4 a = *reinterpret_cast<const float4*>(p0);
            float4 b = *reinterpret_cast<const float4*>(p1);
            v0[0] = a.x; v0[1] = a.y; v0[2] = a.z; v0[3] = a.w;
            v1[0] = b.x; v1[1] = b.y; v1[2] = b.z; v1[3] = b.w;
        } else {
            float2 a = *reinterpret_cast<const float2*>(p0);
            float2 b = *reinterpret_cast<const float2*>(p1);
            v0[0] = a.x; v0[1] = a.y;
            v1[0] = b.x; v1[1] = b.y;
        }
#pragma unroll
        for (int c = 0; c < CPL; ++c) acc[c] += c0 * v0[c] + c1 * v1[c];
    }
    if (e < end) {
        int s0 = srcs[e]; float c0 = coef[e];
        const float* p0 = h + (size_t)s0 * C + lane * CPL;
#pragma unroll
        for (int c = 0; c < CPL; ++c) acc[c] += c0 * p0[c];
    }

    float di = dinv[node];
    float d2 = di * di;
    const float* hs = h + (size_t)node * C + lane * CPL;
    const float* bp = bias + lane * CPL;
    float* op = out + (size_t)node * C + lane * CPL;
    float res[CPL];
#pragma unroll
    for (int c = 0; c < CPL; ++c) {
        float v = di * acc[c] + d2 * hs[c] + bp[c];
        res[c] = APPLY_GELU ? gelu_exact(v) : v;
    }
    if (CPL == 4) {
        float4 o = {res[0], res[1], res[2], res[3]};
        *reinterpret_cast<float4*>(op) = o;
    } else {
        float2 o = {res[0], res[1]};
        *reinterpret_cast<float2*>(op) = o;
    }
}

// ---------------------------------------------------------------------------
extern "C" void kernel_launch(void* const* d_in, const int* in_sizes, int n_in,
                              void* d_out, int out_size, void* d_ws, size_t ws_size,
                              hipStream_t stream) {
    const float* x  = (const float*)d_in[0];
    const int*   ei = (const int*)d_in[1];
    const float* ew = (const float*)d_in[2];
    const float* W1 = (const float*)d_in[3];
    const float* b1 = (const float*)d_in[4];
    const float* W2 = (const float*)d_in[5];
    const float* b2 = (const float*)d_in[6];
    float* out = (float*)d_out;

    int n = in_sizes[0] / CH1;     // 100000
    int E = in_sizes[1] / 2;       // 1600000

    char* ws = (char*)d_ws;
    size_t off = 0;
    auto alloc = [&](size_t bytes) -> void* {
        void* p = ws + off;
        off += (bytes + 255) & ~(size_t)255;
        return p;
    };
    float* dinv     = (float*)alloc((size_t)n * 4);
    int*   counts   = (int*)alloc((size_t)n * 4);
    int*   rowptr   = (int*)alloc((size_t)(n + 1) * 4);
    int*   cursor   = (int*)alloc((size_t)n * 4);
    int    nb       = (n + 255) / 256;
    int*   partials = (int*)alloc((size_t)nb * 4);
    int*   srcs     = (int*)alloc((size_t)E * 4);
    float* coef     = (float*)alloc((size_t)E * 4);
    float* h        = (float*)alloc((size_t)n * CH1 * 4);
    float* x1       = (float*)alloc((size_t)n * CH1 * 4);
    float* h2       = h;   // reuse: h dead after aggregation 1

    int gn = (n + 255) / 256;
    int ge = (E + 255) / 256;

    // CSR build + norm precompute
    init_kernel<<<gn, 256, 0, stream>>>(dinv, counts, n);          // dinv holds deg
    count_kernel<<<ge, 256, 0, stream>>>(ei, ew, dinv, counts, E);
    dinv_kernel<<<gn, 256, 0, stream>>>(dinv, n);
    scan_partial<<<nb, 256, 0, stream>>>(counts, partials, n);
    scan_serial<<<1, 64, 0, stream>>>(partials, nb, rowptr, n);
    scan_final<<<nb, 256, 0, stream>>>(counts, partials, rowptr, cursor, n);
    scatter_kernel<<<ge, 256, 0, stream>>>(ei, ew, dinv, cursor, srcs, coef, E);

    // layer 1: h = x @ W1 ; x1 = gelu(Agg(h) + b1)
    dim3 g1((n + 63) / 64, CH1 / 64);
    gemm_tile<<<g1, 256, 0, stream>>>(x, W1, h, n, CH1, CH1);
    aggregate_kernel<CH1, 1><<<(n + 3) / 4, 256, 0, stream>>>(h, rowptr, srcs, coef,
                                                              dinv, b1, x1, n);

    // layer 2: h2 = x1 @ W2 ; out = Agg(h2) + b2
    dim3 g2((n + 63) / 64, CH2 / 64);
    gemm_tile<<<g2, 256, 0, stream>>>(x1, W2, h2, n, CH2, CH1);
    aggregate_kernel<CH2, 0><<<(n + 3) / 4, 256, 0, stream>>>(h2, rowptr, srcs, coef,
                                                              dinv, b2, out, n);
}

// Round 2
// 624.864 us; speedup vs baseline: 1.6271x; 1.6271x over previous
//
#include <hip/hip_runtime.h>
#include <math.h>

// ---------------------------------------------------------------------------
// GCN: x1 = gelu(Agg(x@W1) + b1); out = Agg(x1@W2) + b2
// Agg(h)[i] = dinv[i] * sum_{e: dst=i} (ew_e * dinv[src_e]) * h[src_e]
//           + dinv[i]^2 * h[i]
// dinv[i] = rsqrt(1 + sum_{e: dst=i} ew_e)
// GEMMs in bf16 MFMA (16x16x32), h/x1 stored bf16, accumulation fp32.
// ---------------------------------------------------------------------------

#define CH1 256
#define CH2 128

using bf16x8 = __attribute__((ext_vector_type(8))) short;
using f32x4  = __attribute__((ext_vector_type(4))) float;

__device__ __forceinline__ ushort f2bf(float f) {
    unsigned u = __float_as_uint(f);
    u = u + 0x7fffu + ((u >> 16) & 1u);   // round-to-nearest-even
    return (ushort)(u >> 16);
}
__device__ __forceinline__ float bf2f(ushort s) {
    return __uint_as_float(((unsigned)s) << 16);
}

// ---------------------------- CSR build ------------------------------------
__global__ void init_kernel(float* deg, int* counts, int n) {
    int i = blockIdx.x * blockDim.x + threadIdx.x;
    if (i < n) { deg[i] = 1.0f; counts[i] = 0; }
}

__global__ void count_kernel(const int* __restrict__ ei, const float* __restrict__ ew,
                             float* deg, int* counts, int E) {
    int e = blockIdx.x * blockDim.x + threadIdx.x;
    if (e < E) {
        int d = ei[E + e];
        atomicAdd(&counts[d], 1);
        atomicAdd(&deg[d], ew[e]);
    }
}

__global__ void dinv_kernel(float* deg, int n) {
    int i = blockIdx.x * blockDim.x + threadIdx.x;
    if (i < n) deg[i] = rsqrtf(deg[i]);
}

__global__ void scan_partial(const int* __restrict__ counts, int* partials, int n) {
    __shared__ int s[256];
    int i = blockIdx.x * 256 + threadIdx.x;
    s[threadIdx.x] = (i < n) ? counts[i] : 0;
    __syncthreads();
    for (int off = 128; off > 0; off >>= 1) {
        if (threadIdx.x < off) s[threadIdx.x] += s[threadIdx.x + off];
        __syncthreads();
    }
    if (threadIdx.x == 0) partials[blockIdx.x] = s[0];
}

__global__ void scan_serial(int* partials, int nb, int* rowptr, int n) {
    if (blockIdx.x == 0 && threadIdx.x == 0) {
        int run = 0;
        for (int i = 0; i < nb; ++i) { int t = partials[i]; partials[i] = run; run += t; }
        rowptr[n] = run;
    }
}

__global__ void scan_final(const int* __restrict__ counts, const int* __restrict__ partials,
                           int* rowptr, int* cursor, int n) {
    __shared__ int s[256];
    int i = blockIdx.x * 256 + threadIdx.x;
    int v = (i < n) ? counts[i] : 0;
    s[threadIdx.x] = v;
    __syncthreads();
    for (int off = 1; off < 256; off <<= 1) {
        int t = (threadIdx.x >= off) ? s[threadIdx.x - off] : 0;
        __syncthreads();
        s[threadIdx.x] += t;
        __syncthreads();
    }
    if (i < n) {
        int excl = partials[blockIdx.x] + s[threadIdx.x] - v;
        rowptr[i] = excl;
        cursor[i] = excl;
    }
}

__global__ void scatter_kernel(const int* __restrict__ ei, const float* __restrict__ ew,
                               const float* __restrict__ dinv, int* cursor,
                               int* __restrict__ src_sorted, float* __restrict__ coef, int E) {
    int e = blockIdx.x * blockDim.x + threadIdx.x;
    if (e < E) {
        int s = ei[e];
        int d = ei[E + e];
        int pos = atomicAdd(&cursor[d], 1);
        src_sorted[pos] = s;
        coef[pos] = ew[e] * dinv[s];
    }
}

// ------------------------- fp32 -> bf16 converts ---------------------------
__global__ void cvt_kernel(const float* __restrict__ in, ushort* __restrict__ out, int n8) {
    int i = blockIdx.x * blockDim.x + threadIdx.x;
    if (i < n8) {
        float4 a = reinterpret_cast<const float4*>(in)[i * 2];
        float4 b = reinterpret_cast<const float4*>(in)[i * 2 + 1];
        uint4 o;
        o.x = (unsigned)f2bf(a.x) | ((unsigned)f2bf(a.y) << 16);
        o.y = (unsigned)f2bf(a.z) | ((unsigned)f2bf(a.w) << 16);
        o.z = (unsigned)f2bf(b.x) | ((unsigned)f2bf(b.y) << 16);
        o.w = (unsigned)f2bf(b.z) | ((unsigned)f2bf(b.w) << 16);
        reinterpret_cast<uint4*>(out)[i] = o;
    }
}

// WT[nn][kk] = bf16(W[kk][nn]);  W is [K][N]
__global__ void transpose_cvt(const float* __restrict__ W, ushort* __restrict__ WT,
                              int K, int N) {
    int idx = blockIdx.x * blockDim.x + threadIdx.x;
    if (idx < K * N) {
        int k = idx / N, nn = idx % N;
        WT[nn * K + k] = f2bf(W[idx]);
    }
}

// --------------------- bf16 MFMA GEMM: C = A @ BT^T ------------------------
// A: [M][K] bf16, BT: [N][K] bf16 (i.e. B transposed), C: [M][N] bf16.
// 128x128 tile, 4 waves (2x2), each wave 64x64 via 4x4 16x16x32 fragments.
__global__ __launch_bounds__(256) void gemm_bf16(const ushort* __restrict__ A,
                                                 const ushort* __restrict__ BT,
                                                 ushort* __restrict__ C,
                                                 int M, int N, int K) {
    __shared__ __align__(16) ushort Als[128 * 32];
    __shared__ __align__(16) ushort Bls[128 * 32];

    const int t = threadIdx.x;
    const int w = t >> 6;
    const int lane = t & 63;
    const int wr = w >> 1, wc = w & 1;
    const int row0 = blockIdx.x * 128;
    const int col0 = blockIdx.y * 128;

    f32x4 acc[4][4] = {};

    for (int k0 = 0; k0 < K; k0 += 32) {
#pragma unroll
        for (int i = 0; i < 2; ++i) {
            int c = (w * 2 + i) * 64 + lane;       // chunk 0..511
            int row = c >> 2;                       // 0..127
            int kg = c & 3;                         // 0..3 (8 bf16 each)
            int arow = row0 + row; if (arow > M - 1) arow = M - 1;
            const ushort* gA = A + (size_t)arow * K + k0 + kg * 8;
            const ushort* gB = BT + (size_t)(col0 + row) * K + k0 + kg * 8;
            __builtin_amdgcn_global_load_lds(
                (const __attribute__((address_space(1))) unsigned*)gA,
                (__attribute__((address_space(3))) unsigned*)&Als[(size_t)(w * 2 + i) * 512],
                16, 0, 0);
            __builtin_amdgcn_global_load_lds(
                (const __attribute__((address_space(1))) unsigned*)gB,
                (__attribute__((address_space(3))) unsigned*)&Bls[(size_t)(w * 2 + i) * 512],
                16, 0, 0);
        }
        __syncthreads();

        bf16x8 afr[4], bfr[4];
#pragma unroll
        for (int m = 0; m < 4; ++m)
            afr[m] = *reinterpret_cast<const bf16x8*>(
                &Als[(wr * 64 + m * 16 + (lane & 15)) * 32 + (lane >> 4) * 8]);
#pragma unroll
        for (int nn = 0; nn < 4; ++nn)
            bfr[nn] = *reinterpret_cast<const bf16x8*>(
                &Bls[(wc * 64 + nn * 16 + (lane & 15)) * 32 + (lane >> 4) * 8]);
#pragma unroll
        for (int m = 0; m < 4; ++m)
#pragma unroll
            for (int nn = 0; nn < 4; ++nn)
                acc[m][nn] = __builtin_amdgcn_mfma_f32_16x16x32_bf16(
                    afr[m], bfr[nn], acc[m][nn], 0, 0, 0);
        __syncthreads();
    }

#pragma unroll
    for (int m = 0; m < 4; ++m) {
#pragma unroll
        for (int nn = 0; nn < 4; ++nn) {
            f32x4 v = acc[m][nn];
            int col = col0 + wc * 64 + nn * 16 + (lane & 15);
#pragma unroll
            for (int j = 0; j < 4; ++j) {
                int row = row0 + wr * 64 + m * 16 + (lane >> 4) * 4 + j;
                if (row < M) C[(size_t)row * N + col] = f2bf(v[j]);
            }
        }
    }
}

__device__ __forceinline__ float gelu_exact(float x) {
    return 0.5f * x * (1.0f + erff(x * 0.70710678118654752f));
}

// -------------------- aggregation over bf16 h ------------------------------
// one wave per node; CPL = C/64 channels per lane
template <int C, int APPLY_GELU, int OUT_BF16>
__global__ __launch_bounds__(256) void aggregate_bf16(
    const ushort* __restrict__ h, const int* __restrict__ rowptr,
    const int* __restrict__ srcs, const float* __restrict__ coef,
    const float* __restrict__ dinv, const float* __restrict__ bias,
    void* __restrict__ outv, int n) {
    constexpr int CPL = C / 64;
    int wid = threadIdx.x >> 6;
    int lane = threadIdx.x & 63;
    int node = blockIdx.x * 4 + wid;
    if (node >= n) return;

    int beg = rowptr[node];
    int end = rowptr[node + 1];
    float acc[CPL];
#pragma unroll
    for (int c = 0; c < CPL; ++c) acc[c] = 0.f;

    int e = beg;
    for (; e + 1 < end; e += 2) {
        int s0 = srcs[e];     float c0 = coef[e];
        int s1 = srcs[e + 1]; float c1 = coef[e + 1];
        ushort v0[CPL], v1[CPL];
        if constexpr (CPL == 4) {
            *(ushort4*)v0 = *reinterpret_cast<const ushort4*>(h + (size_t)s0 * C + lane * 4);
            *(ushort4*)v1 = *reinterpret_cast<const ushort4*>(h + (size_t)s1 * C + lane * 4);
        } else {
            *(ushort2*)v0 = *reinterpret_cast<const ushort2*>(h + (size_t)s0 * C + lane * 2);
            *(ushort2*)v1 = *reinterpret_cast<const ushort2*>(h + (size_t)s1 * C + lane * 2);
        }
#pragma unroll
        for (int c = 0; c < CPL; ++c) acc[c] += c0 * bf2f(v0[c]) + c1 * bf2f(v1[c]);
    }
    if (e < end) {
        int s0 = srcs[e]; float c0 = coef[e];
        ushort v0[CPL];
        if constexpr (CPL == 4)
            *(ushort4*)v0 = *reinterpret_cast<const ushort4*>(h + (size_t)s0 * C + lane * 4);
        else
            *(ushort2*)v0 = *reinterpret_cast<const ushort2*>(h + (size_t)s0 * C + lane * 2);
#pragma unroll
        for (int c = 0; c < CPL; ++c) acc[c] += c0 * bf2f(v0[c]);
    }

    float di = dinv[node];
    float d2 = di * di;
    ushort vs[CPL];
    if constexpr (CPL == 4)
        *(ushort4*)vs = *reinterpret_cast<const ushort4*>(h + (size_t)node * C + lane * 4);
    else
        *(ushort2*)vs = *reinterpret_cast<const ushort2*>(h + (size_t)node * C + lane * 2);

    float res[CPL];
#pragma unroll
    for (int c = 0; c < CPL; ++c) {
        float v = di * acc[c] + d2 * bf2f(vs[c]) + bias[lane * CPL + c];
        res[c] = APPLY_GELU ? gelu_exact(v) : v;
    }

    if constexpr (OUT_BF16) {
        ushort* op = (ushort*)outv + (size_t)node * C + lane * CPL;
        if constexpr (CPL == 4) {
            ushort4 o = {f2bf(res[0]), f2bf(res[1]), f2bf(res[2]), f2bf(res[3])};
            *reinterpret_cast<ushort4*>(op) = o;
        } else {
            ushort2 o = {f2bf(res[0]), f2bf(res[1])};
            *reinterpret_cast<ushort2*>(op) = o;
        }
    } else {
        float* op = (float*)outv + (size_t)node * C + lane * CPL;
        if constexpr (CPL == 4) {
            float4 o = {res[0], res[1], res[2], res[3]};
            *reinterpret_cast<float4*>(op) = o;
        } else {
            float2 o = {res[0], res[1]};
            *reinterpret_cast<float2*>(op) = o;
        }
    }
}

// ---------------------------------------------------------------------------
extern "C" void kernel_launch(void* const* d_in, const int* in_sizes, int n_in,
                              void* d_out, int out_size, void* d_ws, size_t ws_size,
                              hipStream_t stream) {
    const float* x  = (const float*)d_in[0];
    const int*   ei = (const int*)d_in[1];
    const float* ew = (const float*)d_in[2];
    const float* W1 = (const float*)d_in[3];
    const float* b1 = (const float*)d_in[4];
    const float* W2 = (const float*)d_in[5];
    const float* b2 = (const float*)d_in[6];
    float* out = (float*)d_out;

    int n = in_sizes[0] / CH1;     // 100000
    int E = in_sizes[1] / 2;       // 1600000

    char* ws = (char*)d_ws;
    size_t off = 0;
    auto alloc = [&](size_t bytes) -> void* {
        void* p = ws + off;
        off += (bytes + 255) & ~(size_t)255;
        return p;
    };
    float*  dinv     = (float*)alloc((size_t)n * 4);
    int*    counts   = (int*)alloc((size_t)n * 4);
    int*    rowptr   = (int*)alloc((size_t)(n + 1) * 4);
    int*    cursor   = (int*)alloc((size_t)n * 4);
    int     nb       = (n + 255) / 256;
    int*    partials = (int*)alloc((size_t)nb * 4);
    int*    srcs     = (int*)alloc((size_t)E * 4);
    float*  coef     = (float*)alloc((size_t)E * 4);
    ushort* xb       = (ushort*)alloc((size_t)n * CH1 * 2);
    ushort* h        = (ushort*)alloc((size_t)n * CH1 * 2);   // layer1 h, reused as h2
    ushort* x1b      = (ushort*)alloc((size_t)n * CH1 * 2);
    ushort* W1T      = (ushort*)alloc((size_t)CH1 * CH1 * 2);
    ushort* W2T      = (ushort*)alloc((size_t)CH2 * CH1 * 2);

    int gn = (n + 255) / 256;
    int ge = (E + 255) / 256;

    // CSR build + norm precompute
    init_kernel<<<gn, 256, 0, stream>>>(dinv, counts, n);
    count_kernel<<<ge, 256, 0, stream>>>(ei, ew, dinv, counts, E);
    dinv_kernel<<<gn, 256, 0, stream>>>(dinv, n);
    scan_partial<<<nb, 256, 0, stream>>>(counts, partials, n);
    scan_serial<<<1, 64, 0, stream>>>(partials, nb, rowptr, n);
    scan_final<<<nb, 256, 0, stream>>>(counts, partials, rowptr, cursor, n);
    scatter_kernel<<<ge, 256, 0, stream>>>(ei, ew, dinv, cursor, srcs, coef, E);

    // dtype prep
    int n8 = n * CH1 / 8;
    cvt_kernel<<<(n8 + 255) / 256, 256, 0, stream>>>(x, xb, n8);
    transpose_cvt<<<(CH1 * CH1 + 255) / 256, 256, 0, stream>>>(W1, W1T, CH1, CH1);
    transpose_cvt<<<(CH1 * CH2 + 255) / 256, 256, 0, stream>>>(W2, W2T, CH1, CH2);

    // layer 1: h = x @ W1 ; x1 = gelu(Agg(h) + b1)   (bf16)
    dim3 g1((n + 127) / 128, CH1 / 128);
    gemm_bf16<<<g1, 256, 0, stream>>>(xb, W1T, h, n, CH1, CH1);
    aggregate_bf16<CH1, 1, 1><<<(n + 3) / 4, 256, 0, stream>>>(h, rowptr, srcs, coef,
                                                               dinv, b1, x1b, n);

    // layer 2: h2 = x1 @ W2 ; out = Agg(h2) + b2
    dim3 g2((n + 127) / 128, CH2 / 128);
    gemm_bf16<<<g2, 256, 0, stream>>>(x1b, W2T, h, n, CH2, CH1);
    aggregate_bf16<CH2, 0, 0><<<(n + 3) / 4, 256, 0, stream>>>(h, rowptr, srcs, coef,
                                                               dinv, b2, out, n);
}

// Round 3
// 577.693 us; speedup vs baseline: 1.7599x; 1.0817x over previous
//
#include <hip/hip_runtime.h>
#include <math.h>

// ---------------------------------------------------------------------------
// GCN: x1 = gelu(Agg(x@W1) + b1); out = Agg(x1@W2) + b2
// Agg(h)[i] = dinv[i] * sum_{e: dst=i} (ew_e * dinv[src_e]) * h[src_e]
//           + dinv[i]^2 * h[i]
// dinv[i] = rsqrt(1 + sum_{e: dst=i} ew_e)
// GEMMs in bf16 MFMA (16x16x32), h/x1 stored bf16, accumulation fp32.
// Aggregation: CSR of packed {src,coef} pairs, 4-deep gather pipeline.
// ---------------------------------------------------------------------------

#define CH1 256
#define CH2 128

using bf16x8 = __attribute__((ext_vector_type(8))) short;
using f32x4  = __attribute__((ext_vector_type(4))) float;

__device__ __forceinline__ ushort f2bf(float f) {
    unsigned u = __float_as_uint(f);
    u = u + 0x7fffu + ((u >> 16) & 1u);   // round-to-nearest-even
    return (ushort)(u >> 16);
}
__device__ __forceinline__ float bf_lo(unsigned u) {
    return __uint_as_float(u << 16);
}
__device__ __forceinline__ float bf_hi(unsigned u) {
    return __uint_as_float(u & 0xffff0000u);
}

// ---------------------------- CSR build ------------------------------------
__global__ void init_kernel(float* deg, int* counts, int n) {
    int i = blockIdx.x * blockDim.x + threadIdx.x;
    if (i < n) { deg[i] = 1.0f; counts[i] = 0; }
}

__global__ void count_kernel(const int* __restrict__ ei, const float* __restrict__ ew,
                             float* deg, int* counts, int E) {
    int e = blockIdx.x * blockDim.x + threadIdx.x;
    if (e < E) {
        int d = ei[E + e];
        atomicAdd(&counts[d], 1);
        atomicAdd(&deg[d], ew[e]);
    }
}

__global__ void dinv_kernel(float* deg, int n) {
    int i = blockIdx.x * blockDim.x + threadIdx.x;
    if (i < n) deg[i] = rsqrtf(deg[i]);
}

__global__ void scan_partial(const int* __restrict__ counts, int* partials, int n) {
    __shared__ int s[256];
    int i = blockIdx.x * 256 + threadIdx.x;
    s[threadIdx.x] = (i < n) ? counts[i] : 0;
    __syncthreads();
    for (int off = 128; off > 0; off >>= 1) {
        if (threadIdx.x < off) s[threadIdx.x] += s[threadIdx.x + off];
        __syncthreads();
    }
    if (threadIdx.x == 0) partials[blockIdx.x] = s[0];
}

__global__ void scan_serial(int* partials, int nb, int* rowptr, int n) {
    if (blockIdx.x == 0 && threadIdx.x == 0) {
        int run = 0;
        for (int i = 0; i < nb; ++i) { int t = partials[i]; partials[i] = run; run += t; }
        rowptr[n] = run;
    }
}

__global__ void scan_final(const int* __restrict__ counts, const int* __restrict__ partials,
                           int* rowptr, int* cursor, int n) {
    __shared__ int s[256];
    int i = blockIdx.x * 256 + threadIdx.x;
    int v = (i < n) ? counts[i] : 0;
    s[threadIdx.x] = v;
    __syncthreads();
    for (int off = 1; off < 256; off <<= 1) {
        int t = (threadIdx.x >= off) ? s[threadIdx.x - off] : 0;
        __syncthreads();
        s[threadIdx.x] += t;
        __syncthreads();
    }
    if (i < n) {
        int excl = partials[blockIdx.x] + s[threadIdx.x] - v;
        rowptr[i] = excl;
        cursor[i] = excl;
    }
}

// pairs[pos] = {src, bits(ew*dinv[src])} -- one 8B load per edge in aggregation
__global__ void scatter_kernel(const int* __restrict__ ei, const float* __restrict__ ew,
                               const float* __restrict__ dinv, int* cursor,
                               int2* __restrict__ pairs, int E) {
    int e = blockIdx.x * blockDim.x + threadIdx.x;
    if (e < E) {
        int s = ei[e];
        int d = ei[E + e];
        int pos = atomicAdd(&cursor[d], 1);
        int2 p;
        p.x = s;
        p.y = __float_as_int(ew[e] * dinv[s]);
        pairs[pos] = p;
    }
}

// ------------------------- fp32 -> bf16 converts ---------------------------
__global__ void cvt_kernel(const float* __restrict__ in, ushort* __restrict__ out, int n8) {
    int i = blockIdx.x * blockDim.x + threadIdx.x;
    if (i < n8) {
        float4 a = reinterpret_cast<const float4*>(in)[i * 2];
        float4 b = reinterpret_cast<const float4*>(in)[i * 2 + 1];
        uint4 o;
        o.x = (unsigned)f2bf(a.x) | ((unsigned)f2bf(a.y) << 16);
        o.y = (unsigned)f2bf(a.z) | ((unsigned)f2bf(a.w) << 16);
        o.z = (unsigned)f2bf(b.x) | ((unsigned)f2bf(b.y) << 16);
        o.w = (unsigned)f2bf(b.z) | ((unsigned)f2bf(b.w) << 16);
        reinterpret_cast<uint4*>(out)[i] = o;
    }
}

// WT[nn][kk] = bf16(W[kk][nn]);  W is [K][N]
__global__ void transpose_cvt(const float* __restrict__ W, ushort* __restrict__ WT,
                              int K, int N) {
    int idx = blockIdx.x * blockDim.x + threadIdx.x;
    if (idx < K * N) {
        int k = idx / N, nn = idx % N;
        WT[nn * K + k] = f2bf(W[idx]);
    }
}

// --------------------- bf16 MFMA GEMM: C = A @ BT^T ------------------------
// A: [M][K] bf16, BT: [N][K] bf16, C: [M][N] bf16.
// 128x128 tile, 4 waves (2x2), each wave 64x64 via 4x4 16x16x32 fragments.
__global__ __launch_bounds__(256) void gemm_bf16(const ushort* __restrict__ A,
                                                 const ushort* __restrict__ BT,
                                                 ushort* __restrict__ C,
                                                 int M, int N, int K) {
    __shared__ __align__(16) ushort Als[128 * 32];
    __shared__ __align__(16) ushort Bls[128 * 32];

    const int t = threadIdx.x;
    const int w = t >> 6;
    const int lane = t & 63;
    const int wr = w >> 1, wc = w & 1;
    const int row0 = blockIdx.x * 128;
    const int col0 = blockIdx.y * 128;

    f32x4 acc[4][4] = {};

    for (int k0 = 0; k0 < K; k0 += 32) {
#pragma unroll
        for (int i = 0; i < 2; ++i) {
            int c = (w * 2 + i) * 64 + lane;
            int row = c >> 2;
            int kg = c & 3;
            int arow = row0 + row; if (arow > M - 1) arow = M - 1;
            const ushort* gA = A + (size_t)arow * K + k0 + kg * 8;
            const ushort* gB = BT + (size_t)(col0 + row) * K + k0 + kg * 8;
            __builtin_amdgcn_global_load_lds(
                (const __attribute__((address_space(1))) unsigned*)gA,
                (__attribute__((address_space(3))) unsigned*)&Als[(size_t)(w * 2 + i) * 512],
                16, 0, 0);
            __builtin_amdgcn_global_load_lds(
                (const __attribute__((address_space(1))) unsigned*)gB,
                (__attribute__((address_space(3))) unsigned*)&Bls[(size_t)(w * 2 + i) * 512],
                16, 0, 0);
        }
        __syncthreads();

        bf16x8 afr[4], bfr[4];
#pragma unroll
        for (int m = 0; m < 4; ++m)
            afr[m] = *reinterpret_cast<const bf16x8*>(
                &Als[(wr * 64 + m * 16 + (lane & 15)) * 32 + (lane >> 4) * 8]);
#pragma unroll
        for (int nn = 0; nn < 4; ++nn)
            bfr[nn] = *reinterpret_cast<const bf16x8*>(
                &Bls[(wc * 64 + nn * 16 + (lane & 15)) * 32 + (lane >> 4) * 8]);
#pragma unroll
        for (int m = 0; m < 4; ++m)
#pragma unroll
            for (int nn = 0; nn < 4; ++nn)
                acc[m][nn] = __builtin_amdgcn_mfma_f32_16x16x32_bf16(
                    afr[m], bfr[nn], acc[m][nn], 0, 0, 0);
        __syncthreads();
    }

#pragma unroll
    for (int m = 0; m < 4; ++m) {
#pragma unroll
        for (int nn = 0; nn < 4; ++nn) {
            f32x4 v = acc[m][nn];
            int col = col0 + wc * 64 + nn * 16 + (lane & 15);
#pragma unroll
            for (int j = 0; j < 4; ++j) {
                int row = row0 + wr * 64 + m * 16 + (lane >> 4) * 4 + j;
                if (row < M) C[(size_t)row * N + col] = f2bf(v[j]);
            }
        }
    }
}

__device__ __forceinline__ float gelu_exact(float x) {
    return 0.5f * x * (1.0f + erff(x * 0.70710678118654752f));
}

// -------------------- aggregation over bf16 h ------------------------------
// one wave per node; CPL channels/lane; 4-deep software-pipelined gathers.
template <int C, int APPLY_GELU, int OUT_BF16>
__global__ __launch_bounds__(256) void aggregate2(
    const ushort* __restrict__ h, const int* __restrict__ rowptr,
    const int2* __restrict__ pairs,
    const float* __restrict__ dinv, const float* __restrict__ bias,
    void* __restrict__ outv, int n) {
    constexpr int CPL = C / 64;       // 4 (C=256) or 2 (C=128)
    constexpr int UV  = CPL / 2;      // u32 words per gather: 2 or 1
    int wid = threadIdx.x >> 6;
    int lane = threadIdx.x & 63;
    int node = blockIdx.x * 4 + wid;
    if (node >= n) return;

    int beg = rowptr[node];
    int end = rowptr[node + 1];
    float acc[CPL];
#pragma unroll
    for (int c = 0; c < CPL; ++c) acc[c] = 0.f;

    // prologue: prefetch up to 4 pairs
    int2 pr[4];
    int navail = end - beg;
#pragma unroll
    for (int k = 0; k < 4; ++k)
        if (k < navail) pr[k] = pairs[beg + k];

    int e = beg;
    while (e + 4 <= end) {
        // issue all 4 gathers using prefetched indices
        unsigned g[4][UV];
#pragma unroll
        for (int k = 0; k < 4; ++k) {
            const ushort* p = h + (size_t)pr[k].x * C + lane * CPL;
            if constexpr (UV == 2) {
                uint2 v = *reinterpret_cast<const uint2*>(p);
                g[k][0] = v.x; g[k][1] = v.y;
            } else {
                g[k][0] = *reinterpret_cast<const unsigned*>(p);
            }
        }
        float cf[4];
#pragma unroll
        for (int k = 0; k < 4; ++k) cf[k] = __int_as_float(pr[k].y);
        // prefetch next 4 pairs (overlaps gather latency)
#pragma unroll
        for (int k = 0; k < 4; ++k) {
            int idx = e + 4 + k;
            if (idx < end) pr[k] = pairs[idx];
        }
        // accumulate
#pragma unroll
        for (int k = 0; k < 4; ++k) {
#pragma unroll
            for (int u = 0; u < UV; ++u) {
                acc[2 * u]     += cf[k] * bf_lo(g[k][u]);
                acc[2 * u + 1] += cf[k] * bf_hi(g[k][u]);
            }
        }
        e += 4;
    }
    // tail: 0..3 edges, pairs already in pr[]
    int rem = end - e;
#pragma unroll
    for (int k = 0; k < 3; ++k) {
        if (k < rem) {
            float cf = __int_as_float(pr[k].y);
            const ushort* p = h + (size_t)pr[k].x * C + lane * CPL;
#pragma unroll
            for (int u = 0; u < UV; ++u) {
                unsigned v = reinterpret_cast<const unsigned*>(p)[u];
                acc[2 * u]     += cf * bf_lo(v);
                acc[2 * u + 1] += cf * bf_hi(v);
            }
        }
    }

    float di = dinv[node];
    float d2 = di * di;
    const ushort* hs = h + (size_t)node * C + lane * CPL;
    float res[CPL];
#pragma unroll
    for (int u = 0; u < UV; ++u) {
        unsigned v = reinterpret_cast<const unsigned*>(hs)[u];
        float s0 = bf_lo(v), s1 = bf_hi(v);
        float r0 = di * acc[2 * u]     + d2 * s0 + bias[lane * CPL + 2 * u];
        float r1 = di * acc[2 * u + 1] + d2 * s1 + bias[lane * CPL + 2 * u + 1];
        res[2 * u]     = APPLY_GELU ? gelu_exact(r0) : r0;
        res[2 * u + 1] = APPLY_GELU ? gelu_exact(r1) : r1;
    }

    if constexpr (OUT_BF16) {
        ushort* op = (ushort*)outv + (size_t)node * C + lane * CPL;
        if constexpr (CPL == 4) {
            ushort4 o = {f2bf(res[0]), f2bf(res[1]), f2bf(res[2]), f2bf(res[3])};
            *reinterpret_cast<ushort4*>(op) = o;
        } else {
            ushort2 o = {f2bf(res[0]), f2bf(res[1])};
            *reinterpret_cast<ushort2*>(op) = o;
        }
    } else {
        float* op = (float*)outv + (size_t)node * C + lane * CPL;
        if constexpr (CPL == 4) {
            float4 o = {res[0], res[1], res[2], res[3]};
            *reinterpret_cast<float4*>(op) = o;
        } else {
            float2 o = {res[0], res[1]};
            *reinterpret_cast<float2*>(op) = o;
        }
    }
}

// ---------------------------------------------------------------------------
extern "C" void kernel_launch(void* const* d_in, const int* in_sizes, int n_in,
                              void* d_out, int out_size, void* d_ws, size_t ws_size,
                              hipStream_t stream) {
    const float* x  = (const float*)d_in[0];
    const int*   ei = (const int*)d_in[1];
    const float* ew = (const float*)d_in[2];
    const float* W1 = (const float*)d_in[3];
    const float* b1 = (const float*)d_in[4];
    const float* W2 = (const float*)d_in[5];
    const float* b2 = (const float*)d_in[6];
    float* out = (float*)d_out;

    int n = in_sizes[0] / CH1;     // 100000
    int E = in_sizes[1] / 2;       // 1600000

    char* ws = (char*)d_ws;
    size_t off = 0;
    auto alloc = [&](size_t bytes) -> void* {
        void* p = ws + off;
        off += (bytes + 255) & ~(size_t)255;
        return p;
    };
    float*  dinv     = (float*)alloc((size_t)n * 4);
    int*    counts   = (int*)alloc((size_t)n * 4);
    int*    rowptr   = (int*)alloc((size_t)(n + 1) * 4);
    int*    cursor   = (int*)alloc((size_t)n * 4);
    int     nb       = (n + 255) / 256;
    int*    partials = (int*)alloc((size_t)nb * 4);
    int2*   pairs    = (int2*)alloc((size_t)E * 8);
    ushort* xb       = (ushort*)alloc((size_t)n * CH1 * 2);
    ushort* h        = (ushort*)alloc((size_t)n * CH1 * 2);   // layer1 h, reused as h2
    ushort* x1b      = (ushort*)alloc((size_t)n * CH1 * 2);
    ushort* W1T      = (ushort*)alloc((size_t)CH1 * CH1 * 2);
    ushort* W2T      = (ushort*)alloc((size_t)CH2 * CH1 * 2);

    int gn = (n + 255) / 256;
    int ge = (E + 255) / 256;

    // CSR build + norm precompute
    init_kernel<<<gn, 256, 0, stream>>>(dinv, counts, n);
    count_kernel<<<ge, 256, 0, stream>>>(ei, ew, dinv, counts, E);
    dinv_kernel<<<gn, 256, 0, stream>>>(dinv, n);
    scan_partial<<<nb, 256, 0, stream>>>(counts, partials, n);
    scan_serial<<<1, 64, 0, stream>>>(partials, nb, rowptr, n);
    scan_final<<<nb, 256, 0, stream>>>(counts, partials, rowptr, cursor, n);
    scatter_kernel<<<ge, 256, 0, stream>>>(ei, ew, dinv, cursor, pairs, E);

    // dtype prep
    int n8 = n * CH1 / 8;
    cvt_kernel<<<(n8 + 255) / 256, 256, 0, stream>>>(x, xb, n8);
    transpose_cvt<<<(CH1 * CH1 + 255) / 256, 256, 0, stream>>>(W1, W1T, CH1, CH1);
    transpose_cvt<<<(CH1 * CH2 + 255) / 256, 256, 0, stream>>>(W2, W2T, CH1, CH2);

    // layer 1: h = x @ W1 ; x1 = gelu(Agg(h) + b1)   (bf16)
    dim3 g1((n + 127) / 128, CH1 / 128);
    gemm_bf16<<<g1, 256, 0, stream>>>(xb, W1T, h, n, CH1, CH1);
    aggregate2<CH1, 1, 1><<<(n + 3) / 4, 256, 0, stream>>>(h, rowptr, pairs,
                                                           dinv, b1, x1b, n);

    // layer 2: h2 = x1 @ W2 ; out = Agg(h2) + b2
    dim3 g2((n + 127) / 128, CH2 / 128);
    gemm_bf16<<<g2, 256, 0, stream>>>(x1b, W2T, h, n, CH2, CH1);
    aggregate2<CH2, 0, 0><<<(n + 3) / 4, 256, 0, stream>>>(h, rowptr, pairs,
                                                           dinv, b2, out, n);
}

// Round 4
// 492.047 us; speedup vs baseline: 2.0663x; 1.1741x over previous
//
#include <hip/hip_runtime.h>
#include <math.h>

// ---------------------------------------------------------------------------
// GCN: x1 = gelu(Agg(x@W1) + b1); out = Agg(x1@W2) + b2
// Agg(h)[i] = dinv[i] * sum_{e: dst=i} (ew_e * dinv[src_e]) * h[src_e]
//           + dinv[i]^2 * h[i]
// dinv[i] = rsqrt(1 + sum_{e: dst=i} ew_e)
// CSR build: ONE 64-bit atomic per edge (count<<40 | fix24(ew)); the atomic's
// return value gives the edge's rank -> scatter is atomic-free.
// GEMMs bf16 MFMA; aggregation 8-deep software-pipelined gathers.
// ---------------------------------------------------------------------------

#define CH1 256
#define CH2 128

using bf16x8 = __attribute__((ext_vector_type(8))) short;
using f32x4  = __attribute__((ext_vector_type(4))) float;

__device__ __forceinline__ ushort f2bf(float f) {
    unsigned u = __float_as_uint(f);
    u = u + 0x7fffu + ((u >> 16) & 1u);   // round-to-nearest-even
    return (ushort)(u >> 16);
}
__device__ __forceinline__ float bf_lo(unsigned u) {
    return __uint_as_float(u << 16);
}
__device__ __forceinline__ float bf_hi(unsigned u) {
    return __uint_as_float(u & 0xffff0000u);
}

// ---------------------------- CSR build ------------------------------------
__global__ void zero_acc(unsigned long long* acc, int n) {
    int i = blockIdx.x * blockDim.x + threadIdx.x;
    if (i < n) acc[i] = 0ull;
}

// one 64-bit atomic per edge; returned old>>40 = rank of edge within dst list
__global__ void count2_kernel(const int* __restrict__ ei, const float* __restrict__ ew,
                              unsigned long long* __restrict__ acc,
                              int* __restrict__ rank, int E) {
    int e = blockIdx.x * blockDim.x + threadIdx.x;
    if (e < E) {
        int d = ei[E + e];
        unsigned fx = (unsigned)__float2uint_rn(ew[e] * 16777216.0f);  // ew<1 -> <=2^24
        unsigned long long add = (1ull << 40) | (unsigned long long)fx;
        unsigned long long old = atomicAdd(&acc[d], add);
        rank[e] = (int)(old >> 40);
    }
}

// counts[i] = acc>>40 ; dinv[i] = rsqrt(1 + fixed/2^24)
__global__ void extract_kernel(const unsigned long long* __restrict__ acc,
                               int* __restrict__ counts, float* __restrict__ dinv, int n) {
    int i = blockIdx.x * blockDim.x + threadIdx.x;
    if (i < n) {
        unsigned long long v = acc[i];
        counts[i] = (int)(v >> 40);
        float deg = 1.0f + (float)(v & 0xFFFFFFFFFFull) * (1.0f / 16777216.0f);
        dinv[i] = rsqrtf(deg);
    }
}

__global__ void scan_partial(const int* __restrict__ counts, int* partials, int n) {
    __shared__ int s[256];
    int i = blockIdx.x * 256 + threadIdx.x;
    s[threadIdx.x] = (i < n) ? counts[i] : 0;
    __syncthreads();
    for (int off = 128; off > 0; off >>= 1) {
        if (threadIdx.x < off) s[threadIdx.x] += s[threadIdx.x + off];
        __syncthreads();
    }
    if (threadIdx.x == 0) partials[blockIdx.x] = s[0];
}

__global__ void scan_serial(int* partials, int nb, int* rowptr, int n) {
    if (blockIdx.x == 0 && threadIdx.x == 0) {
        int run = 0;
        for (int i = 0; i < nb; ++i) { int t = partials[i]; partials[i] = run; run += t; }
        rowptr[n] = run;
    }
}

__global__ void scan_final(const int* __restrict__ counts, const int* __restrict__ partials,
                           int* rowptr, int n) {
    __shared__ int s[256];
    int i = blockIdx.x * 256 + threadIdx.x;
    int v = (i < n) ? counts[i] : 0;
    s[threadIdx.x] = v;
    __syncthreads();
    for (int off = 1; off < 256; off <<= 1) {
        int t = (threadIdx.x >= off) ? s[threadIdx.x - off] : 0;
        __syncthreads();
        s[threadIdx.x] += t;
        __syncthreads();
    }
    if (i < n) rowptr[i] = partials[blockIdx.x] + s[threadIdx.x] - v;
}

// atomic-free scatter: pos = rowptr[d] + rank[e]
__global__ void scatter2_kernel(const int* __restrict__ ei, const float* __restrict__ ew,
                                const float* __restrict__ dinv,
                                const int* __restrict__ rowptr, const int* __restrict__ rank,
                                int2* __restrict__ pairs, int E) {
    int e = blockIdx.x * blockDim.x + threadIdx.x;
    if (e < E) {
        int s = ei[e];
        int d = ei[E + e];
        int pos = rowptr[d] + rank[e];
        int2 p;
        p.x = s;
        p.y = __float_as_int(ew[e] * dinv[s]);
        pairs[pos] = p;
    }
}

// ------------------------- fp32 -> bf16 converts ---------------------------
__global__ void cvt_kernel(const float* __restrict__ in, ushort* __restrict__ out, int n8) {
    int i = blockIdx.x * blockDim.x + threadIdx.x;
    if (i < n8) {
        float4 a = reinterpret_cast<const float4*>(in)[i * 2];
        float4 b = reinterpret_cast<const float4*>(in)[i * 2 + 1];
        uint4 o;
        o.x = (unsigned)f2bf(a.x) | ((unsigned)f2bf(a.y) << 16);
        o.y = (unsigned)f2bf(a.z) | ((unsigned)f2bf(a.w) << 16);
        o.z = (unsigned)f2bf(b.x) | ((unsigned)f2bf(b.y) << 16);
        o.w = (unsigned)f2bf(b.z) | ((unsigned)f2bf(b.w) << 16);
        reinterpret_cast<uint4*>(out)[i] = o;
    }
}

// WT[nn][kk] = bf16(W[kk][nn]);  W is [K][N]
__global__ void transpose_cvt(const float* __restrict__ W, ushort* __restrict__ WT,
                              int K, int N) {
    int idx = blockIdx.x * blockDim.x + threadIdx.x;
    if (idx < K * N) {
        int k = idx / N, nn = idx % N;
        WT[nn * K + k] = f2bf(W[idx]);
    }
}

// --------------------- bf16 MFMA GEMM: C = A @ BT^T ------------------------
__global__ __launch_bounds__(256) void gemm_bf16(const ushort* __restrict__ A,
                                                 const ushort* __restrict__ BT,
                                                 ushort* __restrict__ C,
                                                 int M, int N, int K) {
    __shared__ __align__(16) ushort Als[128 * 32];
    __shared__ __align__(16) ushort Bls[128 * 32];

    const int t = threadIdx.x;
    const int w = t >> 6;
    const int lane = t & 63;
    const int wr = w >> 1, wc = w & 1;
    const int row0 = blockIdx.x * 128;
    const int col0 = blockIdx.y * 128;

    f32x4 acc[4][4] = {};

    for (int k0 = 0; k0 < K; k0 += 32) {
#pragma unroll
        for (int i = 0; i < 2; ++i) {
            int c = (w * 2 + i) * 64 + lane;
            int row = c >> 2;
            int kg = c & 3;
            int arow = row0 + row; if (arow > M - 1) arow = M - 1;
            const ushort* gA = A + (size_t)arow * K + k0 + kg * 8;
            const ushort* gB = BT + (size_t)(col0 + row) * K + k0 + kg * 8;
            __builtin_amdgcn_global_load_lds(
                (const __attribute__((address_space(1))) unsigned*)gA,
                (__attribute__((address_space(3))) unsigned*)&Als[(size_t)(w * 2 + i) * 512],
                16, 0, 0);
            __builtin_amdgcn_global_load_lds(
                (const __attribute__((address_space(1))) unsigned*)gB,
                (__attribute__((address_space(3))) unsigned*)&Bls[(size_t)(w * 2 + i) * 512],
                16, 0, 0);
        }
        __syncthreads();

        bf16x8 afr[4], bfr[4];
#pragma unroll
        for (int m = 0; m < 4; ++m)
            afr[m] = *reinterpret_cast<const bf16x8*>(
                &Als[(wr * 64 + m * 16 + (lane & 15)) * 32 + (lane >> 4) * 8]);
#pragma unroll
        for (int nn = 0; nn < 4; ++nn)
            bfr[nn] = *reinterpret_cast<const bf16x8*>(
                &Bls[(wc * 64 + nn * 16 + (lane & 15)) * 32 + (lane >> 4) * 8]);
#pragma unroll
        for (int m = 0; m < 4; ++m)
#pragma unroll
            for (int nn = 0; nn < 4; ++nn)
                acc[m][nn] = __builtin_amdgcn_mfma_f32_16x16x32_bf16(
                    afr[m], bfr[nn], acc[m][nn], 0, 0, 0);
        __syncthreads();
    }

#pragma unroll
    for (int m = 0; m < 4; ++m) {
#pragma unroll
        for (int nn = 0; nn < 4; ++nn) {
            f32x4 v = acc[m][nn];
            int col = col0 + wc * 64 + nn * 16 + (lane & 15);
#pragma unroll
            for (int j = 0; j < 4; ++j) {
                int row = row0 + wr * 64 + m * 16 + (lane >> 4) * 4 + j;
                if (row < M) C[(size_t)row * N + col] = f2bf(v[j]);
            }
        }
    }
}

__device__ __forceinline__ float gelu_exact(float x) {
    return 0.5f * x * (1.0f + erff(x * 0.70710678118654752f));
}

// -------------------- aggregation over bf16 h ------------------------------
// one wave per node; CPL channels/lane; 8-deep software-pipelined gathers.
template <int C, int APPLY_GELU, int OUT_BF16>
__global__ __launch_bounds__(256) void aggregate2(
    const ushort* __restrict__ h, const int* __restrict__ rowptr,
    const int2* __restrict__ pairs,
    const float* __restrict__ dinv, const float* __restrict__ bias,
    void* __restrict__ outv, int n) {
    constexpr int CPL = C / 64;       // 4 (C=256) or 2 (C=128)
    constexpr int UV  = CPL / 2;      // u32 words per gather: 2 or 1
    constexpr int D   = 8;            // pipeline depth
    int wid = threadIdx.x >> 6;
    int lane = threadIdx.x & 63;
    int node = blockIdx.x * 4 + wid;
    if (node >= n) return;

    int beg = rowptr[node];
    int end = rowptr[node + 1];
    float acc[CPL];
#pragma unroll
    for (int c = 0; c < CPL; ++c) acc[c] = 0.f;

    int2 pr[D];
    int navail = end - beg;
#pragma unroll
    for (int k = 0; k < D; ++k)
        if (k < navail) pr[k] = pairs[beg + k];

    int e = beg;
    while (e + D <= end) {
        unsigned g[D][UV];
#pragma unroll
        for (int k = 0; k < D; ++k) {
            const ushort* p = h + (size_t)pr[k].x * C + lane * CPL;
            if constexpr (UV == 2) {
                uint2 v = *reinterpret_cast<const uint2*>(p);
                g[k][0] = v.x; g[k][1] = v.y;
            } else {
                g[k][0] = *reinterpret_cast<const unsigned*>(p);
            }
        }
        float cf[D];
#pragma unroll
        for (int k = 0; k < D; ++k) cf[k] = __int_as_float(pr[k].y);
#pragma unroll
        for (int k = 0; k < D; ++k) {
            int idx = e + D + k;
            if (idx < end) pr[k] = pairs[idx];
        }
#pragma unroll
        for (int k = 0; k < D; ++k) {
#pragma unroll
            for (int u = 0; u < UV; ++u) {
                acc[2 * u]     += cf[k] * bf_lo(g[k][u]);
                acc[2 * u + 1] += cf[k] * bf_hi(g[k][u]);
            }
        }
        e += D;
    }
    int rem = end - e;
#pragma unroll
    for (int k = 0; k < D - 1; ++k) {
        if (k < rem) {
            float cf = __int_as_float(pr[k].y);
            const ushort* p = h + (size_t)pr[k].x * C + lane * CPL;
#pragma unroll
            for (int u = 0; u < UV; ++u) {
                unsigned v = reinterpret_cast<const unsigned*>(p)[u];
                acc[2 * u]     += cf * bf_lo(v);
                acc[2 * u + 1] += cf * bf_hi(v);
            }
        }
    }

    float di = dinv[node];
    float d2 = di * di;
    const ushort* hs = h + (size_t)node * C + lane * CPL;
    float res[CPL];
#pragma unroll
    for (int u = 0; u < UV; ++u) {
        unsigned v = reinterpret_cast<const unsigned*>(hs)[u];
        float s0 = bf_lo(v), s1 = bf_hi(v);
        float r0 = di * acc[2 * u]     + d2 * s0 + bias[lane * CPL + 2 * u];
        float r1 = di * acc[2 * u + 1] + d2 * s1 + bias[lane * CPL + 2 * u + 1];
        res[2 * u]     = APPLY_GELU ? gelu_exact(r0) : r0;
        res[2 * u + 1] = APPLY_GELU ? gelu_exact(r1) : r1;
    }

    if constexpr (OUT_BF16) {
        ushort* op = (ushort*)outv + (size_t)node * C + lane * CPL;
        if constexpr (CPL == 4) {
            ushort4 o = {f2bf(res[0]), f2bf(res[1]), f2bf(res[2]), f2bf(res[3])};
            *reinterpret_cast<ushort4*>(op) = o;
        } else {
            ushort2 o = {f2bf(res[0]), f2bf(res[1])};
            *reinterpret_cast<ushort2*>(op) = o;
        }
    } else {
        float* op = (float*)outv + (size_t)node * C + lane * CPL;
        if constexpr (CPL == 4) {
            float4 o = {res[0], res[1], res[2], res[3]};
            *reinterpret_cast<float4*>(op) = o;
        } else {
            float2 o = {res[0], res[1]};
            *reinterpret_cast<float2*>(op) = o;
        }
    }
}

// ---------------------------------------------------------------------------
extern "C" void kernel_launch(void* const* d_in, const int* in_sizes, int n_in,
                              void* d_out, int out_size, void* d_ws, size_t ws_size,
                              hipStream_t stream) {
    const float* x  = (const float*)d_in[0];
    const int*   ei = (const int*)d_in[1];
    const float* ew = (const float*)d_in[2];
    const float* W1 = (const float*)d_in[3];
    const float* b1 = (const float*)d_in[4];
    const float* W2 = (const float*)d_in[5];
    const float* b2 = (const float*)d_in[6];
    float* out = (float*)d_out;

    int n = in_sizes[0] / CH1;     // 100000
    int E = in_sizes[1] / 2;       // 1600000

    char* ws = (char*)d_ws;
    size_t off = 0;
    auto alloc = [&](size_t bytes) -> void* {
        void* p = ws + off;
        off += (bytes + 255) & ~(size_t)255;
        return p;
    };
    unsigned long long* acc64 = (unsigned long long*)alloc((size_t)n * 8);
    float*  dinv     = (float*)alloc((size_t)n * 4);
    int*    counts   = (int*)alloc((size_t)n * 4);
    int*    rowptr   = (int*)alloc((size_t)(n + 1) * 4);
    int*    rank     = (int*)alloc((size_t)E * 4);
    int     nb       = (n + 255) / 256;
    int*    partials = (int*)alloc((size_t)nb * 4);
    int2*   pairs    = (int2*)alloc((size_t)E * 8);
    ushort* xb       = (ushort*)alloc((size_t)n * CH1 * 2);
    ushort* h        = (ushort*)alloc((size_t)n * CH1 * 2);   // layer1 h, reused as h2
    ushort* x1b      = (ushort*)alloc((size_t)n * CH1 * 2);
    ushort* W1T      = (ushort*)alloc((size_t)CH1 * CH1 * 2);
    ushort* W2T      = (ushort*)alloc((size_t)CH2 * CH1 * 2);

    int gn = (n + 255) / 256;
    int ge = (E + 255) / 256;

    // CSR build + norm precompute (one atomic per edge)
    zero_acc<<<gn, 256, 0, stream>>>(acc64, n);
    count2_kernel<<<ge, 256, 0, stream>>>(ei, ew, acc64, rank, E);
    extract_kernel<<<gn, 256, 0, stream>>>(acc64, counts, dinv, n);
    scan_partial<<<nb, 256, 0, stream>>>(counts, partials, n);
    scan_serial<<<1, 64, 0, stream>>>(partials, nb, rowptr, n);
    scan_final<<<nb, 256, 0, stream>>>(counts, partials, rowptr, n);
    scatter2_kernel<<<ge, 256, 0, stream>>>(ei, ew, dinv, rowptr, rank, pairs, E);

    // dtype prep
    int n8 = n * CH1 / 8;
    cvt_kernel<<<(n8 + 255) / 256, 256, 0, stream>>>(x, xb, n8);
    transpose_cvt<<<(CH1 * CH1 + 255) / 256, 256, 0, stream>>>(W1, W1T, CH1, CH1);
    transpose_cvt<<<(CH1 * CH2 + 255) / 256, 256, 0, stream>>>(W2, W2T, CH1, CH2);

    // layer 1: h = x @ W1 ; x1 = gelu(Agg(h) + b1)   (bf16)
    dim3 g1((n + 127) / 128, CH1 / 128);
    gemm_bf16<<<g1, 256, 0, stream>>>(xb, W1T, h, n, CH1, CH1);
    aggregate2<CH1, 1, 1><<<(n + 3) / 4, 256, 0, stream>>>(h, rowptr, pairs,
                                                           dinv, b1, x1b, n);

    // layer 2: h2 = x1 @ W2 ; out = Agg(h2) + b2
    dim3 g2((n + 127) / 128, CH2 / 128);
    gemm_bf16<<<g2, 256, 0, stream>>>(x1b, W2T, h, n, CH2, CH1);
    aggregate2<CH2, 0, 0><<<(n + 3) / 4, 256, 0, stream>>>(h, rowptr, pairs,
                                                           dinv, b2, out, n);
}

// Round 5
// 482.658 us; speedup vs baseline: 2.1064x; 1.0195x over previous
//
#include <hip/hip_runtime.h>
#include <math.h>

// ---------------------------------------------------------------------------
// GCN: x1 = gelu(Agg(x@W1) + b1); out = Agg(x1@W2) + b2
// Agg(h)[i] = dinv[i] * sum_{e: dst=i} (ew_e * dinv[src_e]) * h[src_e]
//           + dinv[i]^2 * h[i]
// dinv[i] = rsqrt(1 + sum_{e: dst=i} ew_e)
// CSR build: ONE 64-bit atomic per edge (count<<40 | fix24(ew)), 4 edges per
// thread for atomic MLP; x->bf16 convert fused into the same launch (streams
// while atomic waves wait on fabric). Scatter is atomic-free via rank;
// weight transposes fused into the scatter launch.
// GEMMs bf16 MFMA; aggregation 8-deep software-pipelined gathers
// (TCC-fill-bound at ~3.26 TB/s: 405 MB = 8 XCDs x 51 MB h, structural).
// ---------------------------------------------------------------------------

#define CH1 256
#define CH2 128

using bf16x8 = __attribute__((ext_vector_type(8))) short;
using f32x4  = __attribute__((ext_vector_type(4))) float;

__device__ __forceinline__ ushort f2bf(float f) {
    unsigned u = __float_as_uint(f);
    u = u + 0x7fffu + ((u >> 16) & 1u);   // round-to-nearest-even
    return (ushort)(u >> 16);
}
__device__ __forceinline__ float bf_lo(unsigned u) {
    return __uint_as_float(u << 16);
}
__device__ __forceinline__ float bf_hi(unsigned u) {
    return __uint_as_float(u & 0xffff0000u);
}

// ---------------------------- CSR build ------------------------------------
__global__ void zero_acc(unsigned long long* acc, int n) {
    int i = blockIdx.x * blockDim.x + threadIdx.x;
    if (i < n) acc[i] = 0ull;
}

// blocks [0,EB): 4 edges/thread, 4 atomics in flight; blocks [EB,..): x->bf16
__global__ __launch_bounds__(256) void fused_count_cvt(
    const int* __restrict__ ei, const float* __restrict__ ew,
    unsigned long long* __restrict__ acc, int* __restrict__ rank,
    int E, int EB,
    const float* __restrict__ x, ushort* __restrict__ xb, int n8) {
    int bid = blockIdx.x;
    if (bid < EB) {
        int base = bid * 256 + threadIdx.x;
        int stride = EB * 256;
        int e[4]; int d[4]; float w[4];
#pragma unroll
        for (int k = 0; k < 4; ++k) e[k] = base + k * stride;
#pragma unroll
        for (int k = 0; k < 4; ++k)
            if (e[k] < E) { d[k] = ei[E + e[k]]; w[k] = ew[e[k]]; }
        unsigned long long old[4];
#pragma unroll
        for (int k = 0; k < 4; ++k)
            if (e[k] < E) {
                unsigned fx = (unsigned)__float2uint_rn(w[k] * 16777216.0f);
                old[k] = atomicAdd(&acc[d[k]],
                                   (1ull << 40) | (unsigned long long)fx);
            }
#pragma unroll
        for (int k = 0; k < 4; ++k)
            if (e[k] < E) rank[e[k]] = (int)(old[k] >> 40);
    } else {
        int i = (bid - EB) * 256 + threadIdx.x;
        if (i < n8) {
            float4 a = reinterpret_cast<const float4*>(x)[i * 2];
            float4 b = reinterpret_cast<const float4*>(x)[i * 2 + 1];
            uint4 o;
            o.x = (unsigned)f2bf(a.x) | ((unsigned)f2bf(a.y) << 16);
            o.y = (unsigned)f2bf(a.z) | ((unsigned)f2bf(a.w) << 16);
            o.z = (unsigned)f2bf(b.x) | ((unsigned)f2bf(b.y) << 16);
            o.w = (unsigned)f2bf(b.z) | ((unsigned)f2bf(b.w) << 16);
            reinterpret_cast<uint4*>(xb)[i] = o;
        }
    }
}

// counts[i] = acc>>40 ; dinv[i] = rsqrt(1 + fixed/2^24)
__global__ void extract_kernel(const unsigned long long* __restrict__ acc,
                               int* __restrict__ counts, float* __restrict__ dinv, int n) {
    int i = blockIdx.x * blockDim.x + threadIdx.x;
    if (i < n) {
        unsigned long long v = acc[i];
        counts[i] = (int)(v >> 40);
        float deg = 1.0f + (float)(v & 0xFFFFFFFFFFull) * (1.0f / 16777216.0f);
        dinv[i] = rsqrtf(deg);
    }
}

__global__ void scan_partial(const int* __restrict__ counts, int* partials, int n) {
    __shared__ int s[256];
    int i = blockIdx.x * 256 + threadIdx.x;
    s[threadIdx.x] = (i < n) ? counts[i] : 0;
    __syncthreads();
    for (int off = 128; off > 0; off >>= 1) {
        if (threadIdx.x < off) s[threadIdx.x] += s[threadIdx.x + off];
        __syncthreads();
    }
    if (threadIdx.x == 0) partials[blockIdx.x] = s[0];
}

__global__ void scan_serial(int* partials, int nb, int* rowptr, int n) {
    if (blockIdx.x == 0 && threadIdx.x == 0) {
        int run = 0;
        for (int i = 0; i < nb; ++i) { int t = partials[i]; partials[i] = run; run += t; }
        rowptr[n] = run;
    }
}

__global__ void scan_final(const int* __restrict__ counts, const int* __restrict__ partials,
                           int* rowptr, int n) {
    __shared__ int s[256];
    int i = blockIdx.x * 256 + threadIdx.x;
    int v = (i < n) ? counts[i] : 0;
    s[threadIdx.x] = v;
    __syncthreads();
    for (int off = 1; off < 256; off <<= 1) {
        int t = (threadIdx.x >= off) ? s[threadIdx.x - off] : 0;
        __syncthreads();
        s[threadIdx.x] += t;
        __syncthreads();
    }
    if (i < n) rowptr[i] = partials[blockIdx.x] + s[threadIdx.x] - v;
}

// blocks [0,SB): atomic-free scatter; then W1T blocks; then W2T blocks.
__global__ __launch_bounds__(256) void scatter_fused(
    const int* __restrict__ ei, const float* __restrict__ ew,
    const float* __restrict__ dinv,
    const int* __restrict__ rowptr, const int* __restrict__ rank,
    int2* __restrict__ pairs, int E, int SB,
    const float* __restrict__ W1, ushort* __restrict__ W1T, int w1n, int W1B,
    const float* __restrict__ W2, ushort* __restrict__ W2T, int w2n) {
    int bid = blockIdx.x;
    if (bid < SB) {
        int e = bid * 256 + threadIdx.x;
        if (e < E) {
            int s = ei[e];
            int d = ei[E + e];
            int pos = rowptr[d] + rank[e];
            int2 p;
            p.x = s;
            p.y = __float_as_int(ew[e] * dinv[s]);
            pairs[pos] = p;
        }
    } else if (bid < SB + W1B) {
        int idx = (bid - SB) * 256 + threadIdx.x;
        if (idx < w1n) {
            int k = idx / CH1, nn = idx % CH1;          // W1 is [CH1][CH1]
            W1T[nn * CH1 + k] = f2bf(W1[idx]);
        }
    } else {
        int idx = (bid - SB - W1B) * 256 + threadIdx.x;
        if (idx < w2n) {
            int k = idx / CH2, nn = idx % CH2;          // W2 is [CH1][CH2]
            W2T[nn * CH1 + k] = f2bf(W2[idx]);
        }
    }
}

// --------------------- bf16 MFMA GEMM: C = A @ BT^T ------------------------
__global__ __launch_bounds__(256) void gemm_bf16(const ushort* __restrict__ A,
                                                 const ushort* __restrict__ BT,
                                                 ushort* __restrict__ C,
                                                 int M, int N, int K) {
    __shared__ __align__(16) ushort Als[128 * 32];
    __shared__ __align__(16) ushort Bls[128 * 32];

    const int t = threadIdx.x;
    const int w = t >> 6;
    const int lane = t & 63;
    const int wr = w >> 1, wc = w & 1;
    const int row0 = blockIdx.x * 128;
    const int col0 = blockIdx.y * 128;

    f32x4 acc[4][4] = {};

    for (int k0 = 0; k0 < K; k0 += 32) {
#pragma unroll
        for (int i = 0; i < 2; ++i) {
            int c = (w * 2 + i) * 64 + lane;
            int row = c >> 2;
            int kg = c & 3;
            int arow = row0 + row; if (arow > M - 1) arow = M - 1;
            const ushort* gA = A + (size_t)arow * K + k0 + kg * 8;
            const ushort* gB = BT + (size_t)(col0 + row) * K + k0 + kg * 8;
            __builtin_amdgcn_global_load_lds(
                (const __attribute__((address_space(1))) unsigned*)gA,
                (__attribute__((address_space(3))) unsigned*)&Als[(size_t)(w * 2 + i) * 512],
                16, 0, 0);
            __builtin_amdgcn_global_load_lds(
                (const __attribute__((address_space(1))) unsigned*)gB,
                (__attribute__((address_space(3))) unsigned*)&Bls[(size_t)(w * 2 + i) * 512],
                16, 0, 0);
        }
        __syncthreads();

        bf16x8 afr[4], bfr[4];
#pragma unroll
        for (int m = 0; m < 4; ++m)
            afr[m] = *reinterpret_cast<const bf16x8*>(
                &Als[(wr * 64 + m * 16 + (lane & 15)) * 32 + (lane >> 4) * 8]);
#pragma unroll
        for (int nn = 0; nn < 4; ++nn)
            bfr[nn] = *reinterpret_cast<const bf16x8*>(
                &Bls[(wc * 64 + nn * 16 + (lane & 15)) * 32 + (lane >> 4) * 8]);
#pragma unroll
        for (int m = 0; m < 4; ++m)
#pragma unroll
            for (int nn = 0; nn < 4; ++nn)
                acc[m][nn] = __builtin_amdgcn_mfma_f32_16x16x32_bf16(
                    afr[m], bfr[nn], acc[m][nn], 0, 0, 0);
        __syncthreads();
    }

#pragma unroll
    for (int m = 0; m < 4; ++m) {
#pragma unroll
        for (int nn = 0; nn < 4; ++nn) {
            f32x4 v = acc[m][nn];
            int col = col0 + wc * 64 + nn * 16 + (lane & 15);
#pragma unroll
            for (int j = 0; j < 4; ++j) {
                int row = row0 + wr * 64 + m * 16 + (lane >> 4) * 4 + j;
                if (row < M) C[(size_t)row * N + col] = f2bf(v[j]);
            }
        }
    }
}

__device__ __forceinline__ float gelu_exact(float x) {
    return 0.5f * x * (1.0f + erff(x * 0.70710678118654752f));
}

// -------------------- aggregation over bf16 h ------------------------------
template <int C, int APPLY_GELU, int OUT_BF16>
__global__ __launch_bounds__(256) void aggregate2(
    const ushort* __restrict__ h, const int* __restrict__ rowptr,
    const int2* __restrict__ pairs,
    const float* __restrict__ dinv, const float* __restrict__ bias,
    void* __restrict__ outv, int n) {
    constexpr int CPL = C / 64;       // 4 (C=256) or 2 (C=128)
    constexpr int UV  = CPL / 2;      // u32 words per gather: 2 or 1
    constexpr int D   = 8;            // pipeline depth
    int wid = threadIdx.x >> 6;
    int lane = threadIdx.x & 63;
    int node = blockIdx.x * 4 + wid;
    if (node >= n) return;

    int beg = rowptr[node];
    int end = rowptr[node + 1];
    float acc[CPL];
#pragma unroll
    for (int c = 0; c < CPL; ++c) acc[c] = 0.f;

    int2 pr[D];
    int navail = end - beg;
#pragma unroll
    for (int k = 0; k < D; ++k)
        if (k < navail) pr[k] = pairs[beg + k];

    int e = beg;
    while (e + D <= end) {
        unsigned g[D][UV];
#pragma unroll
        for (int k = 0; k < D; ++k) {
            const ushort* p = h + (size_t)pr[k].x * C + lane * CPL;
            if constexpr (UV == 2) {
                uint2 v = *reinterpret_cast<const uint2*>(p);
                g[k][0] = v.x; g[k][1] = v.y;
            } else {
                g[k][0] = *reinterpret_cast<const unsigned*>(p);
            }
        }
        float cf[D];
#pragma unroll
        for (int k = 0; k < D; ++k) cf[k] = __int_as_float(pr[k].y);
#pragma unroll
        for (int k = 0; k < D; ++k) {
            int idx = e + D + k;
            if (idx < end) pr[k] = pairs[idx];
        }
#pragma unroll
        for (int k = 0; k < D; ++k) {
#pragma unroll
            for (int u = 0; u < UV; ++u) {
                acc[2 * u]     += cf[k] * bf_lo(g[k][u]);
                acc[2 * u + 1] += cf[k] * bf_hi(g[k][u]);
            }
        }
        e += D;
    }
    int rem = end - e;
#pragma unroll
    for (int k = 0; k < D - 1; ++k) {
        if (k < rem) {
            float cf = __int_as_float(pr[k].y);
            const ushort* p = h + (size_t)pr[k].x * C + lane * CPL;
#pragma unroll
            for (int u = 0; u < UV; ++u) {
                unsigned v = reinterpret_cast<const unsigned*>(p)[u];
                acc[2 * u]     += cf * bf_lo(v);
                acc[2 * u + 1] += cf * bf_hi(v);
            }
        }
    }

    float di = dinv[node];
    float d2 = di * di;
    const ushort* hs = h + (size_t)node * C + lane * CPL;
    float res[CPL];
#pragma unroll
    for (int u = 0; u < UV; ++u) {
        unsigned v = reinterpret_cast<const unsigned*>(hs)[u];
        float s0 = bf_lo(v), s1 = bf_hi(v);
        float r0 = di * acc[2 * u]     + d2 * s0 + bias[lane * CPL + 2 * u];
        float r1 = di * acc[2 * u + 1] + d2 * s1 + bias[lane * CPL + 2 * u + 1];
        res[2 * u]     = APPLY_GELU ? gelu_exact(r0) : r0;
        res[2 * u + 1] = APPLY_GELU ? gelu_exact(r1) : r1;
    }

    if constexpr (OUT_BF16) {
        ushort* op = (ushort*)outv + (size_t)node * C + lane * CPL;
        if constexpr (CPL == 4) {
            ushort4 o = {f2bf(res[0]), f2bf(res[1]), f2bf(res[2]), f2bf(res[3])};
            *reinterpret_cast<ushort4*>(op) = o;
        } else {
            ushort2 o = {f2bf(res[0]), f2bf(res[1])};
            *reinterpret_cast<ushort2*>(op) = o;
        }
    } else {
        float* op = (float*)outv + (size_t)node * C + lane * CPL;
        if constexpr (CPL == 4) {
            float4 o = {res[0], res[1], res[2], res[3]};
            *reinterpret_cast<float4*>(op) = o;
        } else {
            float2 o = {res[0], res[1]};
            *reinterpret_cast<float2*>(op) = o;
        }
    }
}

// ---------------------------------------------------------------------------
extern "C" void kernel_launch(void* const* d_in, const int* in_sizes, int n_in,
                              void* d_out, int out_size, void* d_ws, size_t ws_size,
                              hipStream_t stream) {
    const float* x  = (const float*)d_in[0];
    const int*   ei = (const int*)d_in[1];
    const float* ew = (const float*)d_in[2];
    const float* W1 = (const float*)d_in[3];
    const float* b1 = (const float*)d_in[4];
    const float* W2 = (const float*)d_in[5];
    const float* b2 = (const float*)d_in[6];
    float* out = (float*)d_out;

    int n = in_sizes[0] / CH1;     // 100000
    int E = in_sizes[1] / 2;       // 1600000

    char* ws = (char*)d_ws;
    size_t off = 0;
    auto alloc = [&](size_t bytes) -> void* {
        void* p = ws + off;
        off += (bytes + 255) & ~(size_t)255;
        return p;
    };
    unsigned long long* acc64 = (unsigned long long*)alloc((size_t)n * 8);
    float*  dinv     = (float*)alloc((size_t)n * 4);
    int*    counts   = (int*)alloc((size_t)n * 4);
    int*    rowptr   = (int*)alloc((size_t)(n + 1) * 4);
    int*    rank     = (int*)alloc((size_t)E * 4);
    int     nb       = (n + 255) / 256;
    int*    partials = (int*)alloc((size_t)nb * 4);
    int2*   pairs    = (int2*)alloc((size_t)E * 8);
    ushort* xb       = (ushort*)alloc((size_t)n * CH1 * 2);
    ushort* h        = (ushort*)alloc((size_t)n * CH1 * 2);   // layer1 h, reused as h2
    ushort* x1b      = (ushort*)alloc((size_t)n * CH1 * 2);
    ushort* W1T      = (ushort*)alloc((size_t)CH1 * CH1 * 2);
    ushort* W2T      = (ushort*)alloc((size_t)CH2 * CH1 * 2);

    int gn = (n + 255) / 256;

    // CSR build + norm precompute; x->bf16 convert rides in the same launch
    int EB = (E + 1023) / 1024;            // 4 edges per thread
    int n8 = n * CH1 / 8;
    int CB = (n8 + 255) / 256;
    zero_acc<<<gn, 256, 0, stream>>>(acc64, n);
    fused_count_cvt<<<EB + CB, 256, 0, stream>>>(ei, ew, acc64, rank, E, EB, x, xb, n8);
    extract_kernel<<<gn, 256, 0, stream>>>(acc64, counts, dinv, n);
    scan_partial<<<nb, 256, 0, stream>>>(counts, partials, n);
    scan_serial<<<1, 64, 0, stream>>>(partials, nb, rowptr, n);
    scan_final<<<nb, 256, 0, stream>>>(counts, partials, rowptr, n);

    // scatter + both weight transposes in one launch
    int SB  = (E + 255) / 256;
    int w1n = CH1 * CH1, W1B = (w1n + 255) / 256;
    int w2n = CH1 * CH2, W2B = (w2n + 255) / 256;
    scatter_fused<<<SB + W1B + W2B, 256, 0, stream>>>(ei, ew, dinv, rowptr, rank,
                                                      pairs, E, SB,
                                                      W1, W1T, w1n, W1B,
                                                      W2, W2T, w2n);

    // layer 1: h = x @ W1 ; x1 = gelu(Agg(h) + b1)   (bf16)
    dim3 g1((n + 127) / 128, CH1 / 128);
    gemm_bf16<<<g1, 256, 0, stream>>>(xb, W1T, h, n, CH1, CH1);
    aggregate2<CH1, 1, 1><<<(n + 3) / 4, 256, 0, stream>>>(h, rowptr, pairs,
                                                           dinv, b1, x1b, n);

    // layer 2: h2 = x1 @ W2 ; out = Agg(h2) + b2
    dim3 g2((n + 127) / 128, CH2 / 128);
    gemm_bf16<<<g2, 256, 0, stream>>>(x1b, W2T, h, n, CH2, CH1);
    aggregate2<CH2, 0, 0><<<(n + 3) / 4, 256, 0, stream>>>(h, rowptr, pairs,
                                                           dinv, b2, out, n);
}